// Round 6
// baseline (383.120 us; speedup 1.0000x reference)
//
#include <hip/hip_runtime.h>
#include <math.h>

#define BB 32
#define HH 128
#define SS 8192

typedef __attribute__((ext_vector_type(8))) short bf8;
typedef __attribute__((ext_vector_type(4))) float f4;

static __device__ __forceinline__ unsigned short f2bf(float x) {
  union { float f; unsigned int u; } c; c.f = x;
  unsigned int r = c.u + 0x7FFFu + ((c.u >> 16) & 1u);  // RNE
  return (unsigned short)(r >> 16);
}

// ---------------- prep: bias[b][h] = W[h, 256:384] . dec[b]; Abf = bf16(W[:,0:256]) ----------------
__global__ __launch_bounds__(256) void prep_kernel(
    const float* __restrict__ W, const float* __restrict__ dec,
    unsigned short* __restrict__ Abf, float* __restrict__ bias) {
  const int b = blockIdx.x;
  const int tid = threadIdx.x;
  if (tid < HH) {
    const float* wr = W + (size_t)tid * 384 + 256;
    const float* db = dec + (size_t)b * HH;
    float acc = 0.f;
    #pragma unroll 8
    for (int j = 0; j < HH; ++j) acc += wr[j] * db[j];
    bias[b * HH + tid] = acc;
  }
  if (b == 0) {
    for (int idx = tid; idx < HH * 256; idx += 256) {
      int h = idx >> 8, k = idx & 255;
      Abf[idx] = f2bf(W[h * 384 + k]);
    }
  }
}

// ---------------- main: scores[b][s] = sum_h v[h] * tanh(A@X + bias) ----------------
// 1024-thread blocks = 16 independent waves; one __syncthreads (after A staging).
// __launch_bounds__(1024,8): 64-VGPR cap (kernel needs ~52) -> 8 waves/SIMD,
// 2 blocks/CU (2x64KB LDS), 32 waves/CU: enough fill to hide ~900cy HBM latency
// with the 1-step register prefetch. A (128x256 bf16) in LDS, XOR-swizzled 16B
// chunks; fragment reads are ds_read_b128 on lgkmcnt, decoupled from the vmcnt
// B-stream. Each wave owns a 16-wide s strip (acc = 32 regs).
__global__ __launch_bounds__(1024, 8) void attn_main(
    const float* __restrict__ sta, const float* __restrict__ dyn,
    const unsigned short* __restrict__ Abf, const float* __restrict__ bias,
    const float* __restrict__ v, float* __restrict__ scores) {
  __shared__ unsigned short LA[128 * 256];   // 64 KB, swizzled

  const int tid  = threadIdx.x;
  const int l    = tid & 63;
  const int quad = l >> 4;
  const int n16  = l & 15;
  const int gw   = (blockIdx.x << 4) + (tid >> 6);  // global wave id
  const int b    = gw >> 9;
  const int tile = gw & 511;               // 512 tiles of 16 columns
  const int s0   = tile << 4;

  // ---- stage A: global (bf16) -> LDS, 16B chunks, phys_chunk = ck ^ (m & 7) ----
  #pragma unroll
  for (int j = 0; j < 4; ++j) {
    int gc = (j << 10) + tid;           // 0..4095 chunk id; m = gc>>5, ck = gc&31
    int m = gc >> 5, ck = gc & 31;
    bf8 val = *(const bf8*)(Abf + ((size_t)gc << 3));
    *(bf8*)&LA[m * 256 + ((ck ^ (m & 7)) << 3)] = val;
  }
  __syncthreads();

  const size_t base = ((size_t)b << 20) + (size_t)(quad << 3) * SS + s0 + n16;
  const float* p0 = sta + base;          // rows quad*8.., chunk 0 (k 0..127)
  const float* p1 = dyn + base;          // chunk 1 (k 128..255)

  f4 acc[8];
  #pragma unroll
  for (int mt = 0; mt < 8; ++mt) acc[mt] = (f4){0.f, 0.f, 0.f, 0.f};

  float tmp[8];
  bf8 cur;

  auto issueB = [&](int step) {
    const float* tp = (step < 4 ? p0 : p1) + ((size_t)((step & 3) << 5)) * SS;
    #pragma unroll
    for (int j = 0; j < 8; ++j)
      tmp[j] = tp[(size_t)j * SS];       // 4 x 64B segments per instr
  };
  auto conv = [&]() {
    #pragma unroll
    for (int j = 0; j < 8; ++j) cur[j] = (short)f2bf(tmp[j]);
  };

  const int swz = n16 & 7;               // == (m & 7) for every mt since m = 16*mt + n16
  issueB(0);
  conv();
  #pragma unroll
  for (int step = 0; step < 8; ++step) {
    if (step < 7) issueB(step + 1);      // HBM loads in flight across this step's MFMAs
    const int koff = (((step << 2) + quad) ^ swz) << 3;   // swizzled k-chunk offset (elems)
    #pragma unroll
    for (int mt = 0; mt < 8; ++mt) {
      bf8 af = *(const bf8*)&LA[(((mt << 4) + n16) << 8) + koff];  // ds_read_b128
      acc[mt] = __builtin_amdgcn_mfma_f32_16x16x32_bf16(af, cur, acc[mt], 0, 0, 0);
    }
    if (step < 7) conv();                // waits only on this wave's vmcnt B stream
  }

  // epilogue: z = acc + bias[h]; part += v[h]*tanh(z); reduce over h across quads
  float part = 0.f;
  #pragma unroll
  for (int mt = 0; mt < 8; ++mt) {
    #pragma unroll
    for (int r = 0; r < 4; ++r) {
      const int h = mt * 16 + quad * 4 + r;   // C/D row = quad*4 + reg
      part += v[h] * tanhf(acc[mt][r] + bias[(b << 7) + h]);
    }
  }
  part += __shfl_xor(part, 16, 64);
  part += __shfl_xor(part, 32, 64);
  if (quad == 0)
    scores[((size_t)b << 13) + s0 + n16] = part;
}

// ---------------- softmax over s, in-place on d_out ----------------
__global__ __launch_bounds__(1024) void softmax_kernel(float* __restrict__ out) {
  const int b = blockIdx.x;
  const int tid = threadIdx.x;
  float* row = out + ((size_t)b << 13);
  float4 x0 = ((const float4*)row)[tid];
  float4 x1 = ((const float4*)row)[tid + 1024];
  float lmax = fmaxf(fmaxf(fmaxf(x0.x, x0.y), fmaxf(x0.z, x0.w)),
                     fmaxf(fmaxf(x1.x, x1.y), fmaxf(x1.z, x1.w)));
  __shared__ float red[17];
  #pragma unroll
  for (int o = 32; o >= 1; o >>= 1) lmax = fmaxf(lmax, __shfl_xor(lmax, o, 64));
  if ((tid & 63) == 0) red[tid >> 6] = lmax;
  __syncthreads();
  if (tid < 64) {
    float m = (tid < 16) ? red[tid] : -3.0e38f;
    #pragma unroll
    for (int o = 8; o >= 1; o >>= 1) m = fmaxf(m, __shfl_xor(m, o, 64));
    if (tid == 0) red[16] = m;
  }
  __syncthreads();
  const float gmax = red[16];
  float e[8];
  e[0] = expf(x0.x - gmax); e[1] = expf(x0.y - gmax);
  e[2] = expf(x0.z - gmax); e[3] = expf(x0.w - gmax);
  e[4] = expf(x1.x - gmax); e[5] = expf(x1.y - gmax);
  e[6] = expf(x1.z - gmax); e[7] = expf(x1.w - gmax);
  float ls = e[0] + e[1] + e[2] + e[3] + e[4] + e[5] + e[6] + e[7];
  #pragma unroll
  for (int o = 32; o >= 1; o >>= 1) ls += __shfl_xor(ls, o, 64);
  __syncthreads();   // gmax consumed; safe to reuse red
  if ((tid & 63) == 0) red[tid >> 6] = ls;
  __syncthreads();
  if (tid < 64) {
    float m = (tid < 16) ? red[tid] : 0.f;
    #pragma unroll
    for (int o = 8; o >= 1; o >>= 1) m += __shfl_xor(m, o, 64);
    if (tid == 0) red[16] = m;
  }
  __syncthreads();
  const float inv = 1.0f / red[16];
  float4 o0 = make_float4(e[0] * inv, e[1] * inv, e[2] * inv, e[3] * inv);
  float4 o1 = make_float4(e[4] * inv, e[5] * inv, e[6] * inv, e[7] * inv);
  ((float4*)row)[tid] = o0;
  ((float4*)row)[tid + 1024] = o1;
}

extern "C" void kernel_launch(void* const* d_in, const int* in_sizes, int n_in,
                              void* d_out, int out_size, void* d_ws, size_t ws_size,
                              hipStream_t stream) {
  const float* sta = (const float*)d_in[0];   // (32,128,8192)
  const float* dyn = (const float*)d_in[1];   // (32,128,8192)
  const float* dec = (const float*)d_in[2];   // (32,128)
  const float* v   = (const float*)d_in[3];   // (128)
  const float* W   = (const float*)d_in[4];   // (128,384)

  unsigned short* Abf = (unsigned short*)d_ws;             // 64 KB
  float* bias = (float*)((char*)d_ws + 128 * 256 * 2);     // 16 KB
  float* scores = (float*)d_out;                           // 1 MB, softmaxed in place

  prep_kernel<<<BB, 256, 0, stream>>>(W, dec, Abf, bias);
  attn_main<<<BB * (SS / 16) / 16, 1024, 0, stream>>>(sta, dyn, Abf, bias, v, scores);
  softmax_kernel<<<BB, 1024, 0, stream>>>(scores);
}